// Round 7
// baseline (1551.178 us; speedup 1.0000x reference)
//
#include <hip/hip_runtime.h>
#include <stdint.h>

// WARP loss, B=1024, Y=50000. inputs: input_ f32[B*Y], target f32[B*Y],
// max_num_trials i32[1]; output f32[1] = sum of per-row losses.
//
// Exact-RNG reduction (absmax 0.0 verified on HW, 4 runs): first violator in
// the random permutation == violator with min (u_bits>>9, col); num_trials-1
// == rank == #{cols != pos with key < kstar}.
// Keys are input-independent -> seg blocks push all keys with bits < THR into
// per-row candidate lists (LDS-staged, one global atomic per block) with NO
// input reads; the 9th-arriving contributor block (8 seg + 1 scan, device
// atomic ticket) resolves the row from candidates; rows whose first violator
// lies outside the list take a block-wide full-scan fallback (rare). The last
// row's resolver reduces row_loss -> out[0] in EXACTLY the original order.
#define BN 1024
#define YN 50000
#define SEGS 8              // threefry segments per row
#define SEGLEN 6250         // YN / SEGS
#define CAP_BIG 1024        // THR=2^25: E~390/row, sigma~20 -> never overflows
#define CAP_SMALL 192       // THR=2^23 legacy sizing (ws-constrained path)
#define LCAP 256            // per-block LDS candidate buffer (E~49, sigma~7)

// ---------------- rotl: single v_alignbit_b32 -------------------------------
#if defined(__has_builtin)
#  if __has_builtin(__builtin_amdgcn_alignbit)
#    define ROTL(x, r) __builtin_amdgcn_alignbit((x), (x), 32u - (r))
#  endif
#endif
#ifndef ROTL
#  define ROTL(x, r) (((x) << (r)) | ((x) >> (32 - (r))))
#endif

// ---------------- Threefry-2x32, key (0,42), counter (0, i) -----------------
// tf_core(v) == verified tf_bits(ctr) with v = ctr + 42 (round 1 specialized
// for x0_init == ks0 == 0).
#define TFR(r) { x0 += x1; x1 = ROTL(x1, r) ^ x0; }

__device__ __forceinline__ uint32_t tf_core(uint32_t v) {
    const uint32_t ks1 = 42u;
    const uint32_t ks2 = 0x1BD11BDAu ^ 42u;
    uint32_t x0 = v;
    uint32_t x1 = (ROTL(v, 13u)) ^ v;
    TFR(15u) TFR(26u) TFR(6u)
    x0 += ks1; x1 += ks2 + 1u;
    TFR(17u) TFR(29u) TFR(16u) TFR(24u)
    x0 += ks2; x1 += 2u;                  // ks0 == 0
    TFR(13u) TFR(15u) TFR(26u) TFR(6u)
    /* x0 += ks0 */ x1 += ks1 + 3u;
    TFR(17u) TFR(29u) TFR(16u) TFR(24u)
    x0 += ks1; x1 += ks2 + 4u;
    TFR(13u) TFR(15u) TFR(26u) TFR(6u)
    x0 += ks2; x1 += 5u;                  // ks0 == 0
    return x0 ^ x1;
}

// ws layout (4B units):
//   cnt[BN]      @ 0      \
//   ready[BN]    @ BN      } zeroed by the in-graph memset (12 KB)
//   done(+pad)   @ 2*BN   /
//   pos[BN]      @ 3*BN
//   ps[BN]       @ 4*BN
//   row_loss[BN] @ 5*BN
//   cand[BN*cap] @ 6*BN
struct WS {
    uint32_t* cnt; uint32_t* ready; uint32_t* done;
    int* pos; float* ps; float* row_loss; uint32_t* cand;
};
static inline WS ws_layout(void* d_ws) {
    uint32_t* p = (uint32_t*)d_ws;
    WS w;
    w.cnt = p; w.ready = p + BN; w.done = p + 2 * BN;
    w.pos = (int*)(p + 3 * BN); w.ps = (float*)(p + 4 * BN);
    w.row_loss = (float*)(p + 5 * BN);
    w.cand = p + 6 * BN;
    return w;
}

// ---------------- block-wide resolve (256 threads, one row) -----------------
// min / rank are order-free; loss formula identical to verified version;
// row_loss written once by tid 0 -> bitwise-identical results.
__device__ void block_resolve(
    int row, int tid, const float* __restrict__ input,
    const uint32_t* __restrict__ cnt, const uint32_t* __restrict__ cand,
    const int* __restrict__ pos_, const float* __restrict__ ps_,
    uint32_t mt, float* __restrict__ row_loss, int cap,
    uint32_t* s_u32, uint64_t* s_u64)
{
    const uint32_t n = cnt[row];
    const int pos = pos_[row];
    const float ps = ps_[row];
    const float* rowp = input + (size_t)row * YN;
    bool fb = (n > (uint32_t)cap);

    if (!fb) {
        const uint32_t* cl = cand + (size_t)row * (size_t)cap;
        uint32_t mk = 0xFFFFFFFFu;        // unreachable for real entries
        for (uint32_t i = tid; i < n; i += 256) {
            uint32_t e = cl[i];
            int col = (int)(e & 0xFFFFu);
            if (col != pos) {
                float s = rowp[col];
                if ((1.0f + s) - ps >= 0.0f) mk = (e < mk) ? e : mk;
            }
        }
        s_u32[tid] = mk;
        __syncthreads();
        for (int st = 128; st > 0; st >>= 1) {
            if (tid < st) { uint32_t o = s_u32[tid + st]; if (o < s_u32[tid]) s_u32[tid] = o; }
            __syncthreads();
        }
        mk = s_u32[0];
        __syncthreads();
        if (mk == 0xFFFFFFFFu) {
            fb = true;                    // first violator not in list (or none)
        } else {
            uint32_t c = 0;
            for (uint32_t i = tid; i < n; i += 256) {
                uint32_t e = cl[i];
                int col = (int)(e & 0xFFFFu);
                c += ((e < mk) && (col != pos)) ? 1u : 0u;
            }
            s_u32[tid] = c;
            __syncthreads();
            for (int st = 128; st > 0; st >>= 1) {
                if (tid < st) s_u32[tid] += s_u32[tid + st];
                __syncthreads();
            }
            if (tid == 0) {
                uint32_t rank = s_u32[0];
                float loss = 0.0f;
                if (rank < mt) {
                    int cstar = (int)(mk & 0xFFFFu);
                    float ns = rowp[cstar];
                    float nt = (float)(rank + 1u);
                    loss = logf(floorf(49999.0f / nt)) * ((1.0f - ps) + ns);
                }
                row_loss[row] = loss;
            }
            __syncthreads();
        }
    }
    if (fb) {
        // block-wide full scan (rare: P(rank>coverage) ~ 1e-4 per row-iter)
        const uint32_t fb32 = (uint32_t)row * YN;
        uint64_t mk64 = ~0ull;
        for (int col = tid; col < YN; col += 256) {
            uint32_t bits = tf_core(fb32 + (uint32_t)col + 42u);
            uint64_t key = ((uint64_t)(bits >> 9) << 16) | (uint32_t)col;
            float m = (1.0f + rowp[col]) - ps;
            if ((m >= 0.0f) && (col != pos) && (key < mk64)) mk64 = key;
        }
        s_u64[tid] = mk64;
        __syncthreads();
        for (int st = 128; st > 0; st >>= 1) {
            if (tid < st) { uint64_t o = s_u64[tid + st]; if (o < s_u64[tid]) s_u64[tid] = o; }
            __syncthreads();
        }
        const uint64_t kstar = s_u64[0];
        __syncthreads();
        if (kstar == ~0ull) {
            if (tid == 0) row_loss[row] = 0.0f;
        } else {
            uint32_t c = 0;
            for (int col = tid; col < YN; col += 256) {
                uint32_t bits = tf_core(fb32 + (uint32_t)col + 42u);
                uint64_t key = ((uint64_t)(bits >> 9) << 16) | (uint32_t)col;
                c += ((key < kstar) && (col != pos)) ? 1u : 0u;
            }
            s_u32[tid] = c;
            __syncthreads();
            for (int st = 128; st > 0; st >>= 1) {
                if (tid < st) s_u32[tid] += s_u32[tid + st];
                __syncthreads();
            }
            if (tid == 0) {
                uint32_t rank = s_u32[0];
                float fl = 0.0f;
                if (rank < mt) {
                    int cstar = (int)(kstar & 0xFFFFull);
                    float ns = rowp[cstar];
                    float nt = (float)(rank + 1u);
                    fl = logf(floorf(49999.0f / nt)) * ((1.0f - ps) + ns);
                }
                row_loss[row] = fl;
            }
        }
        __syncthreads();
    }
}

// ---------------- single fused kernel ---------------------------------------
// blocks [0, BN): target scan, one row each (dispatched first).
// blocks [BN, BN + BN*SEGS): threefry over one row segment, LDS-staged push.
// Every block then bumps its row's arrival ticket; the 9th arrival resolves
// the row inline; the last-resolved row's block reduces row_loss -> out[0].
__global__ __launch_bounds__(256) void warp_kernel(
    const float* __restrict__ input, const float* __restrict__ target,
    uint32_t* __restrict__ cnt, uint32_t* __restrict__ ready,
    uint32_t* __restrict__ done, uint32_t* __restrict__ cand,
    int* __restrict__ pos_out, float* __restrict__ ps_out,
    const int* __restrict__ mt_ptr, float* __restrict__ row_loss,
    float* __restrict__ out, uint32_t thr, int cap)
{
    const int tid = threadIdx.x;
    int myrow;

    __shared__ uint32_t s_buf[LCAP];
    __shared__ uint32_t s_cnt, s_base;
    __shared__ uint32_t s_u32[256];
    __shared__ uint64_t s_u64[256];
    __shared__ uint32_t s_tkt;

    if (blockIdx.x < BN) {
        // ---- target scan role ----
        const int row = blockIdx.x;
        myrow = row;
        const size_t base = (size_t)row * YN;
        __shared__ volatile int s_pos;
        if (tid == 0) s_pos = -1;
        __syncthreads();
        const float4* t4 = (const float4*)(target + base);
        for (int j4 = tid; j4 < YN / 4; j4 += 256) {
            if (s_pos >= 0) break;               // benign racy early-exit
            float4 v = t4[j4];
            int c0 = 4 * j4;
            if (v.x != 0.0f) s_pos = c0;
            if (v.y != 0.0f) s_pos = c0 + 1;
            if (v.z != 0.0f) s_pos = c0 + 2;
            if (v.w != 0.0f) s_pos = c0 + 3;
        }
        __syncthreads();
        if (tid == 0) {
            int p = s_pos;
            pos_out[row] = p;
            ps_out[row] = input[base + p];
        }
    } else {
        // ---- threefry role: 24 strides of 256 (=6144) + tail of 106 ----
        const int b = blockIdx.x - BN;
        const int row = b >> 3;                  // b / SEGS
        myrow = row;
        const int seg = b & 7;                   // b % SEGS
        const uint32_t base32 = (uint32_t)row * YN;
        const int start = seg * SEGLEN;
        if (tid == 0) s_cnt = 0;
        __syncthreads();

        int col = start + tid;
        uint32_t cb = base32 + (uint32_t)col;    // counter for chain 0
        for (int k = 0; k < 6; ++k) {
            uint32_t b0 = tf_core(cb + 42u);
            uint32_t b1 = tf_core(cb + 298u);    // 256 + 42
            uint32_t b2 = tf_core(cb + 554u);    // 512 + 42
            uint32_t b3 = tf_core(cb + 810u);    // 768 + 42
            // pack (keyhi, col): bits < 2^25 -> (bits>>9) < 2^16; col < 2^16.
            if (b0 < thr) {
                uint32_t i = atomicAdd(&s_cnt, 1u);
                if (i < LCAP) s_buf[i] = ((b0 >> 9) << 16) | (uint32_t)col;
            }
            if (b1 < thr) {
                uint32_t i = atomicAdd(&s_cnt, 1u);
                if (i < LCAP) s_buf[i] = ((b1 >> 9) << 16) | (uint32_t)(col + 256);
            }
            if (b2 < thr) {
                uint32_t i = atomicAdd(&s_cnt, 1u);
                if (i < LCAP) s_buf[i] = ((b2 >> 9) << 16) | (uint32_t)(col + 512);
            }
            if (b3 < thr) {
                uint32_t i = atomicAdd(&s_cnt, 1u);
                if (i < LCAP) s_buf[i] = ((b3 >> 9) << 16) | (uint32_t)(col + 768);
            }
            col += 1024; cb += 1024u;
        }
        if (tid < SEGLEN - 6144) {               // tail: 106 cols
            uint32_t bt = tf_core(cb + 42u);
            if (bt < thr) {
                uint32_t i = atomicAdd(&s_cnt, 1u);
                if (i < LCAP) s_buf[i] = ((bt >> 9) << 16) | (uint32_t)col;
            }
        }
        __syncthreads();

        // ---- flush: one global atomic reserves a chunk; coalesced copy ----
        const uint32_t tot = s_cnt;
        if (tid == 0) {
            if (tot > LCAP) {                    // statistically unreachable
                atomicAdd(cnt + row, 1u << 20);  // force row fallback
                s_base = 0xFFFFFFFFu;
            } else {
                s_base = atomicAdd(cnt + row, tot);
            }
        }
        __syncthreads();
        const uint32_t base_ = s_base;
        if (base_ != 0xFFFFFFFFu) {
            uint32_t* mycand = cand + (size_t)row * (size_t)cap;
            for (uint32_t i = tid; i < tot; i += 256) {
                uint32_t gi = base_ + i;
                if (gi < (uint32_t)cap) mycand[gi] = s_buf[i];
            }
        }
    }

    // ---- per-row arrival ticket: 9 contributors (8 seg + 1 scan) ----
    __syncthreads();
    if (tid == 0) {
        __threadfence();                         // release cand/cnt/pos/ps
        s_tkt = atomicAdd(ready + myrow, 1u);
    }
    __syncthreads();
    if (s_tkt != SEGS) return;                   // not the 9th arrival

    // ---- 9th arrival: resolve this row with the whole block ----
    __threadfence();                             // acquire all contributions
    const uint32_t mt = (uint32_t)mt_ptr[0];
    block_resolve(myrow, tid, input, cnt, cand, pos_out, ps_out,
                  mt, row_loss, cap, s_u32, s_u64);

    // ---- row-done ticket: last-resolved row reduces (original order) ----
    __syncthreads();
    if (tid == 0) {
        __threadfence();                         // release row_loss
        s_tkt = atomicAdd(done, 1u);
    }
    __syncthreads();
    if (s_tkt != (uint32_t)(BN - 1)) return;

    __threadfence();                             // acquire all row_loss
    __shared__ float s[256];
    float acc = 0.0f;
    for (int i = tid; i < BN; i += 256) acc += row_loss[i];
    s[tid] = acc;
    __syncthreads();
    for (int st = 128; st > 0; st >>= 1) {
        if (tid < st) s[tid] += s[tid + st];
        __syncthreads();
    }
    if (tid == 0) out[0] = s[0];
}

extern "C" void kernel_launch(void* const* d_in, const int* in_sizes, int n_in,
                              void* d_out, int out_size, void* d_ws, size_t ws_size,
                              hipStream_t stream) {
    const float* input  = (const float*)d_in[0];
    const float* target = (const float*)d_in[1];
    const int*   mt     = (const int*)d_in[2];
    float* out = (float*)d_out;
    WS w = ws_layout(d_ws);

    // big path: THR=2^25 (E~390 cand/row, CAP 1024) needs ~4.2 MB of ws;
    // guard against a small workspace with the verified legacy sizing.
    const size_t need_big = (size_t)(6 * BN) * 4 + (size_t)BN * CAP_BIG * 4;
    uint32_t thr; int cap;
    if (ws_size >= need_big) { thr = 1u << 25; cap = CAP_BIG; }
    else                     { thr = 1u << 23; cap = CAP_SMALL; }

    // zero cnt + ready + done (harness poisons ws with 0xAA before launch)
    hipMemsetAsync(d_ws, 0, 3 * BN * sizeof(uint32_t), stream);

    warp_kernel<<<BN + BN * SEGS, 256, 0, stream>>>(
        input, target, w.cnt, w.ready, w.done, w.cand,
        w.pos, w.ps, mt, w.row_loss, out, thr, cap);
}

// Round 8
// 460.203 us; speedup vs baseline: 3.3706x; 3.3706x over previous
//
#include <hip/hip_runtime.h>
#include <stdint.h>

// WARP loss, B=1024, Y=50000. inputs: input_ f32[B*Y], target f32[B*Y],
// max_num_trials i32[1]; output f32[1] = sum of per-row losses.
//
// Exact-RNG reduction (absmax 0.0 verified on HW, 5 runs): first violator in
// the random permutation == violator with min (u_bits>>9, col); num_trials-1
// == rank == #{cols != pos with key < kstar}.
//
// R8: ONE block per row does everything row-locally (scan pos -> threefry all
// 50K cols, candidates with bits < THR=2^25 staged in LDS (E~390, cap 1024)
// -> resolve from LDS -> row_loss). No cross-block handoff except the
// verified done-ticket final reduce (1024 release fences on 4B each + 1
// acquire -- R5-scale, harmless; R7 showed ~10K fences = disaster).
// Rows whose first violator is outside the candidate set (all violator keys
// >= THR, P ~ e^-{k/128} summed over rows << 1 per iter) take a block-wide
// full-scan fallback: if the true first violator is not in the list, no
// in-list candidate violates, so the fallback triggers -- correct for any THR.
#define BN 1024
#define YN 50000
#define THR (1u << 25)      // candidate threshold on raw bits
#define RCAP 1024           // per-row LDS candidate cap (E~390, sigma~20)

// ---------------- rotl: single v_alignbit_b32 -------------------------------
#if defined(__has_builtin)
#  if __has_builtin(__builtin_amdgcn_alignbit)
#    define ROTL(x, r) __builtin_amdgcn_alignbit((x), (x), 32u - (r))
#  endif
#endif
#ifndef ROTL
#  define ROTL(x, r) (((x) << (r)) | ((x) >> (32 - (r))))
#endif

// ---------------- Threefry-2x32, key (0,42), counter (0, i) -----------------
// tf_core(v) == verified tf_bits(ctr) with v = ctr + 42 (round 1 specialized
// for x0_init == ks0 == 0).
#define TFR(r) { x0 += x1; x1 = ROTL(x1, r) ^ x0; }

__device__ __forceinline__ uint32_t tf_core(uint32_t v) {
    const uint32_t ks1 = 42u;
    const uint32_t ks2 = 0x1BD11BDAu ^ 42u;
    uint32_t x0 = v;
    uint32_t x1 = (ROTL(v, 13u)) ^ v;
    TFR(15u) TFR(26u) TFR(6u)
    x0 += ks1; x1 += ks2 + 1u;
    TFR(17u) TFR(29u) TFR(16u) TFR(24u)
    x0 += ks2; x1 += 2u;                  // ks0 == 0
    TFR(13u) TFR(15u) TFR(26u) TFR(6u)
    /* x0 += ks0 */ x1 += ks1 + 3u;
    TFR(17u) TFR(29u) TFR(16u) TFR(24u)
    x0 += ks1; x1 += ks2 + 4u;
    TFR(13u) TFR(15u) TFR(26u) TFR(6u)
    x0 += ks2; x1 += 5u;                  // ks0 == 0
    return x0 ^ x1;
}

#define PUSH(bits, colv)                                                    \
    if ((bits) < THR) {                                                     \
        uint32_t x_ = atomicAdd(&s_cnt, 1u);                                \
        if (x_ < RCAP) s_buf[x_] = (((bits) >> 9) << 16) | (uint32_t)(colv);\
    }

// ws layout: row_loss[BN] @ 0, done @ BN (zeroed by in-graph 4B memset).
__global__ __launch_bounds__(256) void warp_rowkernel(
    const float* __restrict__ input, const float* __restrict__ target,
    const int* __restrict__ mt_ptr, float* __restrict__ row_loss,
    uint32_t* __restrict__ done, float* __restrict__ out)
{
    const int tid = threadIdx.x;
    const int row = blockIdx.x;
    const size_t base = (size_t)row * YN;
    const float* rowp = input + base;

    __shared__ uint32_t s_buf[RCAP];
    __shared__ uint32_t s_cnt;
    __shared__ volatile int s_pos;
    __shared__ uint32_t s_u32[256];
    __shared__ uint64_t s_u64[256];
    __shared__ float s_red[256];
    __shared__ uint32_t s_tkt;

    if (tid == 0) { s_cnt = 0u; s_pos = -1; }
    __syncthreads();

    // ---- scan target row for the positive's position ----
    const float4* t4 = (const float4*)(target + base);
    for (int j4 = tid; j4 < YN / 4; j4 += 256) {
        if (s_pos >= 0) break;               // benign racy early-exit
        float4 v = t4[j4];
        int c0 = 4 * j4;
        if (v.x != 0.0f) s_pos = c0;
        if (v.y != 0.0f) s_pos = c0 + 1;
        if (v.z != 0.0f) s_pos = c0 + 2;
        if (v.w != 0.0f) s_pos = c0 + 3;
    }
    __syncthreads();
    const int pos = s_pos;
    const float ps = rowp[pos];              // same addr all lanes: broadcast

    // ---- threefry over the whole row: col = tid + 256*j, j in [0,196) ----
    // 48 iters x 4 chains (j=0..191) + 3 chains (j=192..194) + tail (j=195).
    const uint32_t cb0 = (uint32_t)row * (uint32_t)YN + 42u;
    uint32_t c = cb0 + (uint32_t)tid;
    int colb = tid;
#pragma unroll 1
    for (int i = 0; i < 48; ++i) {
        uint32_t b0 = tf_core(c);
        uint32_t b1 = tf_core(c + 256u);
        uint32_t b2 = tf_core(c + 512u);
        uint32_t b3 = tf_core(c + 768u);
        PUSH(b0, colb)
        PUSH(b1, colb + 256)
        PUSH(b2, colb + 512)
        PUSH(b3, colb + 768)
        c += 1024u; colb += 1024;
    }
    {   // j = 192, 193, 194  (colb == tid + 49152)
        uint32_t b0 = tf_core(c);
        uint32_t b1 = tf_core(c + 256u);
        uint32_t b2 = tf_core(c + 512u);
        PUSH(b0, colb)
        PUSH(b1, colb + 256)
        PUSH(b2, colb + 512)
    }
    if (tid < 80) {                          // j = 195: cols 49920..49999
        uint32_t bt = tf_core(c + 768u);
        PUSH(bt, colb + 768)
    }
    __syncthreads();

    // ---- resolve from the LDS candidate list ----
    const uint32_t n = s_cnt;
    const uint32_t mt = (uint32_t)mt_ptr[0];
    bool fb = (n > RCAP);

    if (!fb) {
        uint32_t mk = 0xFFFFFFFFu;           // unreachable for real entries
        for (uint32_t i = tid; i < n; i += 256) {
            uint32_t e = s_buf[i];
            int col = (int)(e & 0xFFFFu);
            if (col != pos) {
                float s = rowp[col];
                if ((1.0f + s) - ps >= 0.0f) mk = (e < mk) ? e : mk;
            }
        }
        s_u32[tid] = mk;
        __syncthreads();
        for (int st = 128; st > 0; st >>= 1) {
            if (tid < st) { uint32_t o = s_u32[tid + st]; if (o < s_u32[tid]) s_u32[tid] = o; }
            __syncthreads();
        }
        mk = s_u32[0];
        __syncthreads();
        if (mk == 0xFFFFFFFFu) {
            fb = true;          // first violator not in list (or none at all)
        } else {
            // rank = #{candidates: key < mk, col != pos}; all keys < mk are
            // below THR, hence in the list -> exact.
            uint32_t cc = 0;
            for (uint32_t i = tid; i < n; i += 256) {
                uint32_t e = s_buf[i];
                int col = (int)(e & 0xFFFFu);
                cc += ((e < mk) && (col != pos)) ? 1u : 0u;
            }
            s_u32[tid] = cc;
            __syncthreads();
            for (int st = 128; st > 0; st >>= 1) {
                if (tid < st) s_u32[tid] += s_u32[tid + st];
                __syncthreads();
            }
            if (tid == 0) {
                uint32_t rank = s_u32[0];
                float loss = 0.0f;
                if (rank < mt) {
                    int cstar = (int)(mk & 0xFFFFu);
                    float ns = rowp[cstar];
                    float nt = (float)(rank + 1u);
                    loss = logf(floorf(49999.0f / nt)) * ((1.0f - ps) + ns);
                }
                row_loss[row] = loss;
            }
            __syncthreads();
        }
    }
    if (fb) {
        // block-wide full scan (rare). 64-bit key (keyhi23 << 16 | col).
        uint64_t mk64 = ~0ull;
        for (int col = tid; col < YN; col += 256) {
            uint32_t bits = tf_core(cb0 + (uint32_t)col);
            uint64_t key = ((uint64_t)(bits >> 9) << 16) | (uint32_t)col;
            float m = (1.0f + rowp[col]) - ps;
            if ((m >= 0.0f) && (col != pos) && (key < mk64)) mk64 = key;
        }
        s_u64[tid] = mk64;
        __syncthreads();
        for (int st = 128; st > 0; st >>= 1) {
            if (tid < st) { uint64_t o = s_u64[tid + st]; if (o < s_u64[tid]) s_u64[tid] = o; }
            __syncthreads();
        }
        const uint64_t kstar = s_u64[0];
        __syncthreads();
        if (kstar == ~0ull) {
            if (tid == 0) row_loss[row] = 0.0f;
        } else {
            uint32_t cc = 0;
            for (int col = tid; col < YN; col += 256) {
                uint32_t bits = tf_core(cb0 + (uint32_t)col);
                uint64_t key = ((uint64_t)(bits >> 9) << 16) | (uint32_t)col;
                cc += ((key < kstar) && (col != pos)) ? 1u : 0u;
            }
            s_u32[tid] = cc;
            __syncthreads();
            for (int st = 128; st > 0; st >>= 1) {
                if (tid < st) s_u32[tid] += s_u32[tid + st];
                __syncthreads();
            }
            if (tid == 0) {
                uint32_t rank = s_u32[0];
                float fl = 0.0f;
                if (rank < mt) {
                    int cstar = (int)(kstar & 0xFFFFull);
                    float ns = rowp[cstar];
                    float nt = (float)(rank + 1u);
                    fl = logf(floorf(49999.0f / nt)) * ((1.0f - ps) + ns);
                }
                row_loss[row] = fl;
            }
        }
        __syncthreads();
    }

    // ---- done-ticket: last block reduces row_loss in EXACT original order --
    if (tid == 0) {
        __threadfence();                     // release row_loss[row] (4B dirty)
        s_tkt = atomicAdd(done, 1u);
    }
    __syncthreads();
    if (s_tkt != (uint32_t)(BN - 1)) return;

    __threadfence();                         // acquire all row_loss
    float acc = 0.0f;
    for (int i = tid; i < BN; i += 256) acc += row_loss[i];
    s_red[tid] = acc;
    __syncthreads();
    for (int st = 128; st > 0; st >>= 1) {
        if (tid < st) s_red[tid] += s_red[tid + st];
        __syncthreads();
    }
    if (tid == 0) out[0] = s_red[0];
}

extern "C" void kernel_launch(void* const* d_in, const int* in_sizes, int n_in,
                              void* d_out, int out_size, void* d_ws, size_t ws_size,
                              hipStream_t stream) {
    const float* input  = (const float*)d_in[0];
    const float* target = (const float*)d_in[1];
    const int*   mt     = (const int*)d_in[2];
    float* out = (float*)d_out;
    float* row_loss = (float*)d_ws;
    uint32_t* done = (uint32_t*)d_ws + BN;

    // zero the done ticket (harness poisons ws with 0xAA before every launch)
    hipMemsetAsync((char*)d_ws + BN * sizeof(float), 0, sizeof(uint32_t), stream);

    warp_rowkernel<<<BN, 256, 0, stream>>>(input, target, mt, row_loss, done, out);
}

// Round 10
// 454.700 us; speedup vs baseline: 3.4114x; 1.0121x over previous
//
#include <hip/hip_runtime.h>
#include <stdint.h>

// WARP loss, B=1024, Y=50000. inputs: input_ f32[B*Y], target f32[B*Y],
// max_num_trials i32[1]; output f32[1] = sum of per-row losses.
//
// Exact-RNG reduction (absmax 0.0 verified on HW, 6 runs): first violator in
// the random permutation == violator with min (u_bits>>9, col); num_trials-1
// == rank == #{cols != pos with key < kstar}.
//
// R10 == R9 with the fused-scan INDEX BUG fixed: R9 loaded t4[(tid+1024i)>>2]
// which covers only 1/4 of the row and mis-derives the position (crash via
// uninitialized s_pos -> wild gather). Correct index: j4 = tid + 256*i,
// c0 = 4*j4. Scan is interleaved with the threefry loop so its memory time
// hides under the ~120us RNG-mandated VALU work (R8 serial phases: 65% busy).
// Candidates with bits < THR=2^25 staged in LDS (E~390, cap 1024); resolve
// from LDS; rare rows whose first violator is outside the candidate set take
// a block-wide full-scan fallback (if the true first violator is not in the
// list, no in-list candidate violates, so the fallback triggers -- correct
// for any THR). Last block (done ticket) reduces row_loss in the EXACT
// original order.
#define BN 1024
#define YN 50000
#define THR (1u << 25)      // candidate threshold on raw bits
#define RCAP 1024           // per-row LDS candidate cap (E~390, sigma~20)

// ---------------- rotl: single v_alignbit_b32 -------------------------------
#if defined(__has_builtin)
#  if __has_builtin(__builtin_amdgcn_alignbit)
#    define ROTL(x, r) __builtin_amdgcn_alignbit((x), (x), 32u - (r))
#  endif
#endif
#ifndef ROTL
#  define ROTL(x, r) (((x) << (r)) | ((x) >> (32 - (r))))
#endif

// ---------------- Threefry-2x32, key (0,42), counter (0, i) -----------------
// tf_core(v) == verified tf_bits(ctr) with v = ctr + 42 (round 1 specialized
// for x0_init == ks0 == 0).
#define TFR(r) { x0 += x1; x1 = ROTL(x1, r) ^ x0; }

__device__ __forceinline__ uint32_t tf_core(uint32_t v) {
    const uint32_t ks1 = 42u;
    const uint32_t ks2 = 0x1BD11BDAu ^ 42u;
    uint32_t x0 = v;
    uint32_t x1 = (ROTL(v, 13u)) ^ v;
    TFR(15u) TFR(26u) TFR(6u)
    x0 += ks1; x1 += ks2 + 1u;
    TFR(17u) TFR(29u) TFR(16u) TFR(24u)
    x0 += ks2; x1 += 2u;                  // ks0 == 0
    TFR(13u) TFR(15u) TFR(26u) TFR(6u)
    /* x0 += ks0 */ x1 += ks1 + 3u;
    TFR(17u) TFR(29u) TFR(16u) TFR(24u)
    x0 += ks1; x1 += ks2 + 4u;
    TFR(13u) TFR(15u) TFR(26u) TFR(6u)
    x0 += ks2; x1 += 5u;                  // ks0 == 0
    return x0 ^ x1;
}

#define PUSH(bits, colv)                                                    \
    if ((bits) < THR) {                                                     \
        uint32_t x_ = atomicAdd(&s_cnt, 1u);                                \
        if (x_ < RCAP) s_buf[x_] = (((bits) >> 9) << 16) | (uint32_t)(colv);\
    }

// ws layout: row_loss[BN] @ 0, done @ BN (zeroed by in-graph 4B memset).
__global__ __launch_bounds__(256) void warp_rowkernel(
    const float* __restrict__ input, const float* __restrict__ target,
    const int* __restrict__ mt_ptr, float* __restrict__ row_loss,
    uint32_t* __restrict__ done, float* __restrict__ out)
{
    const int tid = threadIdx.x;
    const int row = blockIdx.x;
    const size_t base = (size_t)row * YN;
    const float* rowp = input + base;

    __shared__ uint32_t s_buf[RCAP];
    __shared__ uint32_t s_cnt;
    __shared__ int s_pos;                    // single writer (unique nonzero)
    __shared__ uint32_t s_u32[256];
    __shared__ uint64_t s_u64[256];
    __shared__ float s_red[256];
    __shared__ uint32_t s_tkt;

    if (tid == 0) { s_cnt = 0u; s_pos = -1; }
    __syncthreads();

    // ---- fused loop: threefry (4 chains/iter) + interleaved target scan ----
    // hash cols: tid + 1024*i + {0,256,512,768}, i in [0,48) -> 0..49151
    // scan:      j4 = tid + 256*i, i in [0,48)               -> [0,12288)
    const float4* t4 = (const float4*)(target + base);
    const uint32_t cb0 = (uint32_t)row * (uint32_t)YN + 42u;
    uint32_t c = cb0 + (uint32_t)tid;
    int colb = tid;
#pragma unroll 1
    for (int i = 0; i < 48; ++i) {
        const int j4 = tid + (i << 8);       // scan index (INDEPENDENT of colb)
        float4 tv = t4[j4];
        uint32_t b0 = tf_core(c);
        uint32_t b1 = tf_core(c + 256u);
        uint32_t b2 = tf_core(c + 512u);
        uint32_t b3 = tf_core(c + 768u);
        PUSH(b0, colb)
        PUSH(b1, colb + 256)
        PUSH(b2, colb + 512)
        PUSH(b3, colb + 768)
        if (tv.x != 0.0f || tv.y != 0.0f || tv.z != 0.0f || tv.w != 0.0f) {
            int c0 = 4 * j4;
            if (tv.x != 0.0f) s_pos = c0;
            if (tv.y != 0.0f) s_pos = c0 + 1;
            if (tv.z != 0.0f) s_pos = c0 + 2;
            if (tv.w != 0.0f) s_pos = c0 + 3;
        }
        c += 1024u; colb += 1024;
    }
    // scan tail: j4 in [12288, 12500) -> cols 49152..49999
    if (tid < 212) {
        float4 tv = t4[12288 + tid];
        int c0 = 4 * (12288 + tid);
        if (tv.x != 0.0f) s_pos = c0;
        if (tv.y != 0.0f) s_pos = c0 + 1;
        if (tv.z != 0.0f) s_pos = c0 + 2;
        if (tv.w != 0.0f) s_pos = c0 + 3;
    }
    // hash tail: chains j=192,193,194 (colb == tid+49152), then 80 cols
    {
        uint32_t b0 = tf_core(c);
        uint32_t b1 = tf_core(c + 256u);
        uint32_t b2 = tf_core(c + 512u);
        PUSH(b0, colb)
        PUSH(b1, colb + 256)
        PUSH(b2, colb + 512)
    }
    if (tid < 80) {                          // cols 49920..49999
        uint32_t bt = tf_core(c + 768u);
        PUSH(bt, colb + 768)
    }
    __syncthreads();

    int pos = s_pos;
    if (pos < 0) pos = 0;                    // defensive (valid target: never)
    const float ps = rowp[pos];              // same addr all lanes: broadcast

    // ---- resolve from the LDS candidate list ----
    const uint32_t n = s_cnt;
    const uint32_t mt = (uint32_t)mt_ptr[0];
    bool fb = (n > RCAP);

    if (!fb) {
        uint32_t mk = 0xFFFFFFFFu;           // unreachable for real entries
        for (uint32_t i = tid; i < n; i += 256) {
            uint32_t e = s_buf[i];
            int col = (int)(e & 0xFFFFu);
            if (col != pos) {
                float s = rowp[col];
                if ((1.0f + s) - ps >= 0.0f) mk = (e < mk) ? e : mk;
            }
        }
        s_u32[tid] = mk;
        __syncthreads();
        for (int st = 128; st > 0; st >>= 1) {
            if (tid < st) { uint32_t o = s_u32[tid + st]; if (o < s_u32[tid]) s_u32[tid] = o; }
            __syncthreads();
        }
        mk = s_u32[0];
        __syncthreads();
        if (mk == 0xFFFFFFFFu) {
            fb = true;          // first violator not in list (or none at all)
        } else {
            // rank = #{candidates: key < mk, col != pos}; all keys < mk are
            // below THR, hence in the list -> exact.
            uint32_t cc = 0;
            for (uint32_t i = tid; i < n; i += 256) {
                uint32_t e = s_buf[i];
                int col = (int)(e & 0xFFFFu);
                cc += ((e < mk) && (col != pos)) ? 1u : 0u;
            }
            s_u32[tid] = cc;
            __syncthreads();
            for (int st = 128; st > 0; st >>= 1) {
                if (tid < st) s_u32[tid] += s_u32[tid + st];
                __syncthreads();
            }
            if (tid == 0) {
                uint32_t rank = s_u32[0];
                float loss = 0.0f;
                if (rank < mt) {
                    int cstar = (int)(mk & 0xFFFFu);
                    float ns = rowp[cstar];
                    float nt = (float)(rank + 1u);
                    loss = logf(floorf(49999.0f / nt)) * ((1.0f - ps) + ns);
                }
                row_loss[row] = loss;
            }
            __syncthreads();
        }
    }
    if (fb) {
        // block-wide full scan (rare). 64-bit key (keyhi23 << 16 | col).
        uint64_t mk64 = ~0ull;
        for (int col = tid; col < YN; col += 256) {
            uint32_t bits = tf_core(cb0 + (uint32_t)col);
            uint64_t key = ((uint64_t)(bits >> 9) << 16) | (uint32_t)col;
            float m = (1.0f + rowp[col]) - ps;
            if ((m >= 0.0f) && (col != pos) && (key < mk64)) mk64 = key;
        }
        s_u64[tid] = mk64;
        __syncthreads();
        for (int st = 128; st > 0; st >>= 1) {
            if (tid < st) { uint64_t o = s_u64[tid + st]; if (o < s_u64[tid]) s_u64[tid] = o; }
            __syncthreads();
        }
        const uint64_t kstar = s_u64[0];
        __syncthreads();
        if (kstar == ~0ull) {
            if (tid == 0) row_loss[row] = 0.0f;
        } else {
            uint32_t cc = 0;
            for (int col = tid; col < YN; col += 256) {
                uint32_t bits = tf_core(cb0 + (uint32_t)col);
                uint64_t key = ((uint64_t)(bits >> 9) << 16) | (uint32_t)col;
                cc += ((key < kstar) && (col != pos)) ? 1u : 0u;
            }
            s_u32[tid] = cc;
            __syncthreads();
            for (int st = 128; st > 0; st >>= 1) {
                if (tid < st) s_u32[tid] += s_u32[tid + st];
                __syncthreads();
            }
            if (tid == 0) {
                uint32_t rank = s_u32[0];
                float fl = 0.0f;
                if (rank < mt) {
                    int cstar = (int)(kstar & 0xFFFFull);
                    float ns = rowp[cstar];
                    float nt = (float)(rank + 1u);
                    fl = logf(floorf(49999.0f / nt)) * ((1.0f - ps) + ns);
                }
                row_loss[row] = fl;
            }
        }
        __syncthreads();
    }

    // ---- done-ticket: last block reduces row_loss in EXACT original order --
    if (tid == 0) {
        __threadfence();                     // release row_loss[row] (4B dirty)
        s_tkt = atomicAdd(done, 1u);
    }
    __syncthreads();
    if (s_tkt != (uint32_t)(BN - 1)) return;

    __threadfence();                         // acquire all row_loss
    float acc = 0.0f;
    for (int i = tid; i < BN; i += 256) acc += row_loss[i];
    s_red[tid] = acc;
    __syncthreads();
    for (int st = 128; st > 0; st >>= 1) {
        if (tid < st) s_red[tid] += s_red[tid + st];
        __syncthreads();
    }
    if (tid == 0) out[0] = s_red[0];
}

extern "C" void kernel_launch(void* const* d_in, const int* in_sizes, int n_in,
                              void* d_out, int out_size, void* d_ws, size_t ws_size,
                              hipStream_t stream) {
    const float* input  = (const float*)d_in[0];
    const float* target = (const float*)d_in[1];
    const int*   mt     = (const int*)d_in[2];
    float* out = (float*)d_out;
    float* row_loss = (float*)d_ws;
    uint32_t* done = (uint32_t*)d_ws + BN;

    // zero the done ticket (harness poisons ws with 0xAA before every launch)
    hipMemsetAsync((char*)d_ws + BN * sizeof(float), 0, sizeof(uint32_t), stream);

    warp_rowkernel<<<BN, 256, 0, stream>>>(input, target, mt, row_loss, done, out);
}

// Round 11
// 450.739 us; speedup vs baseline: 3.4414x; 1.0088x over previous
//
#include <hip/hip_runtime.h>
#include <stdint.h>

// WARP loss, B=1024, Y=50000. inputs: input_ f32[B*Y], target f32[B*Y],
// max_num_trials i32[1]; output f32[1] = sum of per-row losses.
//
// Exact-RNG reduction (absmax 0.0 verified on HW, 7 runs): first violator in
// the random permutation == violator with min (u_bits>>9, col); num_trials-1
// == rank == #{cols != pos with key < kstar}.
//
// R11 == R10 with 512 threads/block (same 1024 one-block-per-row blocks).
// R10 at 256 thr/blk = 4 waves/SIMD resident -> VALUBusy 64%; R5's gen at 8
// waves/SIMD hit 82% on the same hash count. 512 thr/blk -> 4 blocks/CU x 8
// waves = 32 waves/CU (HW cap) with NO cross-block handoff. Per-thread hash
// work halves; candidate set identical; resolve identical; final reduce
// runs on tid<256 with the EXACT original 256-stride + 256-tree order.
#define BN 1024
#define YN 50000
#define THR (1u << 25)      // candidate threshold on raw bits
#define RCAP 1024           // per-row LDS candidate cap (E~390, sigma~20)
#define NT 512              // threads per block

// ---------------- rotl: single v_alignbit_b32 -------------------------------
#if defined(__has_builtin)
#  if __has_builtin(__builtin_amdgcn_alignbit)
#    define ROTL(x, r) __builtin_amdgcn_alignbit((x), (x), 32u - (r))
#  endif
#endif
#ifndef ROTL
#  define ROTL(x, r) (((x) << (r)) | ((x) >> (32 - (r))))
#endif

// ---------------- Threefry-2x32, key (0,42), counter (0, i) -----------------
// tf_core(v) == verified tf_bits(ctr) with v = ctr + 42 (round 1 specialized
// for x0_init == ks0 == 0).
#define TFR(r) { x0 += x1; x1 = ROTL(x1, r) ^ x0; }

__device__ __forceinline__ uint32_t tf_core(uint32_t v) {
    const uint32_t ks1 = 42u;
    const uint32_t ks2 = 0x1BD11BDAu ^ 42u;
    uint32_t x0 = v;
    uint32_t x1 = (ROTL(v, 13u)) ^ v;
    TFR(15u) TFR(26u) TFR(6u)
    x0 += ks1; x1 += ks2 + 1u;
    TFR(17u) TFR(29u) TFR(16u) TFR(24u)
    x0 += ks2; x1 += 2u;                  // ks0 == 0
    TFR(13u) TFR(15u) TFR(26u) TFR(6u)
    /* x0 += ks0 */ x1 += ks1 + 3u;
    TFR(17u) TFR(29u) TFR(16u) TFR(24u)
    x0 += ks1; x1 += ks2 + 4u;
    TFR(13u) TFR(15u) TFR(26u) TFR(6u)
    x0 += ks2; x1 += 5u;                  // ks0 == 0
    return x0 ^ x1;
}

#define PUSH(bits, colv)                                                    \
    if ((bits) < THR) {                                                     \
        uint32_t x_ = atomicAdd(&s_cnt, 1u);                                \
        if (x_ < RCAP) s_buf[x_] = (((bits) >> 9) << 16) | (uint32_t)(colv);\
    }

// ws layout: row_loss[BN] @ 0, done @ BN (zeroed by in-graph 4B memset).
__global__ __launch_bounds__(NT) void warp_rowkernel(
    const float* __restrict__ input, const float* __restrict__ target,
    const int* __restrict__ mt_ptr, float* __restrict__ row_loss,
    uint32_t* __restrict__ done, float* __restrict__ out)
{
    const int tid = threadIdx.x;
    const int row = blockIdx.x;
    const size_t base = (size_t)row * YN;
    const float* rowp = input + base;

    __shared__ uint32_t s_buf[RCAP];
    __shared__ uint32_t s_cnt;
    __shared__ int s_pos;                    // single writer (unique nonzero)
    __shared__ uint32_t s_u32[NT];
    __shared__ uint64_t s_u64[NT];
    __shared__ float s_red[256];
    __shared__ uint32_t s_tkt;

    if (tid == 0) { s_cnt = 0u; s_pos = -1; }
    __syncthreads();

    // ---- fused loop: threefry (4 chains/iter) + interleaved target scan ----
    // hash cols: tid + 2048*i + {0,512,1024,1536}, i in [0,24) -> 0..49151
    // scan:      j4 = tid + 512*i, i in [0,24)                 -> [0,12288)
    const float4* t4 = (const float4*)(target + base);
    const uint32_t cb0 = (uint32_t)row * (uint32_t)YN + 42u;
    uint32_t c = cb0 + (uint32_t)tid;
    int colb = tid;
#pragma unroll 1
    for (int i = 0; i < 24; ++i) {
        const int j4 = tid + (i << 9);       // scan index (INDEPENDENT of colb)
        float4 tv = t4[j4];
        uint32_t b0 = tf_core(c);
        uint32_t b1 = tf_core(c + 512u);
        uint32_t b2 = tf_core(c + 1024u);
        uint32_t b3 = tf_core(c + 1536u);
        PUSH(b0, colb)
        PUSH(b1, colb + 512)
        PUSH(b2, colb + 1024)
        PUSH(b3, colb + 1536)
        if (tv.x != 0.0f || tv.y != 0.0f || tv.z != 0.0f || tv.w != 0.0f) {
            int c0 = 4 * j4;
            if (tv.x != 0.0f) s_pos = c0;
            if (tv.y != 0.0f) s_pos = c0 + 1;
            if (tv.z != 0.0f) s_pos = c0 + 2;
            if (tv.w != 0.0f) s_pos = c0 + 3;
        }
        c += 2048u; colb += 2048;
    }
    // scan tail: j4 in [12288, 12500) -> cols 49152..49999
    if (tid < 212) {
        float4 tv = t4[12288 + tid];
        int c0 = 4 * (12288 + tid);
        if (tv.x != 0.0f) s_pos = c0;
        if (tv.y != 0.0f) s_pos = c0 + 1;
        if (tv.z != 0.0f) s_pos = c0 + 2;
        if (tv.w != 0.0f) s_pos = c0 + 3;
    }
    // hash tail: colb == tid + 49152; col 49152+tid (all), 49664+tid (<336)
    {
        uint32_t b0 = tf_core(c);
        PUSH(b0, colb)
    }
    if (tid < 336) {                         // cols 49664..49999
        uint32_t b1 = tf_core(c + 512u);
        PUSH(b1, colb + 512)
    }
    __syncthreads();

    int pos = s_pos;
    if (pos < 0) pos = 0;                    // defensive (valid target: never)
    const float ps = rowp[pos];              // same addr all lanes: broadcast

    // ---- resolve from the LDS candidate list ----
    const uint32_t n = s_cnt;
    const uint32_t mt = (uint32_t)mt_ptr[0];
    bool fb = (n > RCAP);

    if (!fb) {
        uint32_t mk = 0xFFFFFFFFu;           // unreachable for real entries
        for (uint32_t i = tid; i < n; i += NT) {
            uint32_t e = s_buf[i];
            int col = (int)(e & 0xFFFFu);
            if (col != pos) {
                float s = rowp[col];
                if ((1.0f + s) - ps >= 0.0f) mk = (e < mk) ? e : mk;
            }
        }
        s_u32[tid] = mk;
        __syncthreads();
        for (int st = NT / 2; st > 0; st >>= 1) {
            if (tid < st) { uint32_t o = s_u32[tid + st]; if (o < s_u32[tid]) s_u32[tid] = o; }
            __syncthreads();
        }
        mk = s_u32[0];
        __syncthreads();
        if (mk == 0xFFFFFFFFu) {
            fb = true;          // first violator not in list (or none at all)
        } else {
            // rank = #{candidates: key < mk, col != pos}; all keys < mk are
            // below THR, hence in the list -> exact.
            uint32_t cc = 0;
            for (uint32_t i = tid; i < n; i += NT) {
                uint32_t e = s_buf[i];
                int col = (int)(e & 0xFFFFu);
                cc += ((e < mk) && (col != pos)) ? 1u : 0u;
            }
            s_u32[tid] = cc;
            __syncthreads();
            for (int st = NT / 2; st > 0; st >>= 1) {
                if (tid < st) s_u32[tid] += s_u32[tid + st];
                __syncthreads();
            }
            if (tid == 0) {
                uint32_t rank = s_u32[0];
                float loss = 0.0f;
                if (rank < mt) {
                    int cstar = (int)(mk & 0xFFFFu);
                    float ns = rowp[cstar];
                    float nt = (float)(rank + 1u);
                    loss = logf(floorf(49999.0f / nt)) * ((1.0f - ps) + ns);
                }
                row_loss[row] = loss;
            }
            __syncthreads();
        }
    }
    if (fb) {
        // block-wide full scan (rare). 64-bit key (keyhi23 << 16 | col).
        uint64_t mk64 = ~0ull;
        for (int col = tid; col < YN; col += NT) {
            uint32_t bits = tf_core(cb0 + (uint32_t)col);
            uint64_t key = ((uint64_t)(bits >> 9) << 16) | (uint32_t)col;
            float m = (1.0f + rowp[col]) - ps;
            if ((m >= 0.0f) && (col != pos) && (key < mk64)) mk64 = key;
        }
        s_u64[tid] = mk64;
        __syncthreads();
        for (int st = NT / 2; st > 0; st >>= 1) {
            if (tid < st) { uint64_t o = s_u64[tid + st]; if (o < s_u64[tid]) s_u64[tid] = o; }
            __syncthreads();
        }
        const uint64_t kstar = s_u64[0];
        __syncthreads();
        if (kstar == ~0ull) {
            if (tid == 0) row_loss[row] = 0.0f;
        } else {
            uint32_t cc = 0;
            for (int col = tid; col < YN; col += NT) {
                uint32_t bits = tf_core(cb0 + (uint32_t)col);
                uint64_t key = ((uint64_t)(bits >> 9) << 16) | (uint32_t)col;
                cc += ((key < kstar) && (col != pos)) ? 1u : 0u;
            }
            s_u32[tid] = cc;
            __syncthreads();
            for (int st = NT / 2; st > 0; st >>= 1) {
                if (tid < st) s_u32[tid] += s_u32[tid + st];
                __syncthreads();
            }
            if (tid == 0) {
                uint32_t rank = s_u32[0];
                float fl = 0.0f;
                if (rank < mt) {
                    int cstar = (int)(kstar & 0xFFFFull);
                    float ns = rowp[cstar];
                    float nt = (float)(rank + 1u);
                    fl = logf(floorf(49999.0f / nt)) * ((1.0f - ps) + ns);
                }
                row_loss[row] = fl;
            }
        }
        __syncthreads();
    }

    // ---- done-ticket: last block reduces row_loss in EXACT original order --
    if (tid == 0) {
        __threadfence();                     // release row_loss[row] (4B dirty)
        s_tkt = atomicAdd(done, 1u);
    }
    __syncthreads();
    if (s_tkt != (uint32_t)(BN - 1)) return;

    __threadfence();                         // acquire all row_loss
    // EXACT original order: 256-stride accumulation + 256-wide tree.
    if (tid < 256) {
        float acc = 0.0f;
        for (int i = tid; i < BN; i += 256) acc += row_loss[i];
        s_red[tid] = acc;
    }
    __syncthreads();
    for (int st = 128; st > 0; st >>= 1) {
        if (tid < st) s_red[tid] += s_red[tid + st];
        __syncthreads();
    }
    if (tid == 0) out[0] = s_red[0];
}

extern "C" void kernel_launch(void* const* d_in, const int* in_sizes, int n_in,
                              void* d_out, int out_size, void* d_ws, size_t ws_size,
                              hipStream_t stream) {
    const float* input  = (const float*)d_in[0];
    const float* target = (const float*)d_in[1];
    const int*   mt     = (const int*)d_in[2];
    float* out = (float*)d_out;
    float* row_loss = (float*)d_ws;
    uint32_t* done = (uint32_t*)d_ws + BN;

    // zero the done ticket (harness poisons ws with 0xAA before every launch)
    hipMemsetAsync((char*)d_ws + BN * sizeof(float), 0, sizeof(uint32_t), stream);

    warp_rowkernel<<<BN, NT, 0, stream>>>(input, target, mt, row_loss, done, out);
}